// Round 2
// baseline (2234.869 us; speedup 1.0000x reference)
//
#include <hip/hip_runtime.h>
#include <hip/hip_bf16.h>

using bf16 = __hip_bfloat16;
typedef __attribute__((ext_vector_type(8))) short bf16x8;
typedef __attribute__((ext_vector_type(4))) float f32x4;

#define B_   2
#define S_   2048
#define D_   2048
#define H_   16
#define HD_  128
#define F_   8192
#define LC_  512
#define ESTRIDE (6*D_)   // em is (B,6,D); per-b stride

// ---------------- block reduction helpers (256 threads, 4 waves) ------------
__device__ __forceinline__ float bsum4(float v, float* rs) {
  #pragma unroll
  for (int o = 32; o; o >>= 1) v += __shfl_down(v, o, 64);
  int lane = threadIdx.x & 63, w = threadIdx.x >> 6;
  if (!lane) rs[w] = v;
  __syncthreads();
  float r = rs[0] + rs[1] + rs[2] + rs[3];
  __syncthreads();
  return r;
}
__device__ __forceinline__ float bmax4(float v, float* rs) {
  #pragma unroll
  for (int o = 32; o; o >>= 1) v = fmaxf(v, __shfl_down(v, o, 64));
  int lane = threadIdx.x & 63, w = threadIdx.x >> 6;
  if (!lane) rs[w] = v;
  __syncthreads();
  float r = fmaxf(fmaxf(rs[0], rs[1]), fmaxf(rs[2], rs[3]));
  __syncthreads();
  return r;
}

// ---------------- small elementwise kernels ---------------------------------
__global__ void k_addmod(const float* __restrict__ e, const float* __restrict__ mod,
                         float* __restrict__ em) {
  int i = blockIdx.x * 256 + threadIdx.x;        // B*6*D total
  em[i] = e[i] + mod[i % (6 * D_)];
}

__global__ void k_f2b(const float* __restrict__ in, bf16* __restrict__ out) {
  int i = blockIdx.x * 256 + threadIdx.x;
  out[i] = __float2bfloat16(in[i]);
}

__global__ void k_copy_f32(const float* __restrict__ in, float* __restrict__ out) {
  int i = blockIdx.x * 256 + threadIdx.x;
  out[i] = in[i];
}

// transpose+convert weights: in (K,N) f32 -> out (N,K) bf16
__global__ void k_tr_f2b(const float* __restrict__ in, bf16* __restrict__ out,
                         int K, int N) {
  __shared__ float tile[64][65];
  int kb = blockIdx.y << 6, nb = blockIdx.x << 6;
  int x = threadIdx.x & 63, y = threadIdx.x >> 6;
  #pragma unroll
  for (int r = y; r < 64; r += 4) tile[r][x] = in[(size_t)(kb + r) * N + nb + x];
  __syncthreads();
  #pragma unroll
  for (int r = y; r < 64; r += 4)
    out[(size_t)(nb + r) * K + kb + x] = __float2bfloat16(tile[x][r]);
}

// bf16 transpose, batched over z: in (R,C) -> out (C,R)
__global__ void k_tr_b2b(const bf16* __restrict__ in, bf16* __restrict__ out,
                         int R, int C, long long sIn, long long sOut) {
  in  += (long long)blockIdx.z * sIn;
  out += (long long)blockIdx.z * sOut;
  __shared__ bf16 tile[64][65];
  int rb = blockIdx.y << 6, cb = blockIdx.x << 6;
  int x = threadIdx.x & 63, y = threadIdx.x >> 6;
  #pragma unroll
  for (int r = y; r < 64; r += 4) tile[r][x] = in[(size_t)(rb + r) * C + cb + x];
  __syncthreads();
  #pragma unroll
  for (int r = y; r < 64; r += 4) out[(size_t)(cb + r) * R + rb + x] = tile[x][r];
}

// tx = LN(x) * (1 + e_i1) + e_i0, one block per row of 2048, bf16 out
__global__ void k_ln_mod(const float* __restrict__ x, const float* __restrict__ em,
                         int i0, int i1, bf16* __restrict__ out, int s_per_b) {
  __shared__ float rs[4];
  int row = blockIdx.x, t = threadIdx.x;
  int b = row / s_per_b;
  const float* xr = x + (size_t)row * D_;
  float vals[8], s = 0.f, ss = 0.f;
  #pragma unroll
  for (int j = 0; j < 8; j++) {
    float v = xr[t + j * 256];
    vals[j] = v; s += v; ss += v * v;
  }
  s  = bsum4(s, rs);
  ss = bsum4(ss, rs);
  float mean = s * (1.f / D_);
  float var  = ss * (1.f / D_) - mean * mean;
  float inv  = rsqrtf(var + 1e-6f);
  const float* e0 = em + ((size_t)b * 6 + i0) * D_;
  const float* e1 = em + ((size_t)b * 6 + i1) * D_;
  bf16* orow = out + (size_t)row * D_;
  #pragma unroll
  for (int j = 0; j < 8; j++) {
    int c = t + j * 256;
    orow[c] = __float2bfloat16((vals[j] - mean) * inv * (1.f + e1[c]) + e0[c]);
  }
}

// in-place rmsnorm over 2048 (+optional RoPE per 128-dim head), bf16 buffer
__global__ void k_rms_rope(bf16* __restrict__ buf, const float* __restrict__ w,
                           const float* __restrict__ freqs, int do_rope, int s_per_b) {
  __shared__ float rs[4];
  int row = blockIdx.x, t = threadIdx.x;
  bf16* pr = buf + (size_t)row * D_;
  float4 raw = *(const float4*)(pr + (size_t)t * 8);
  bf16* hb = (bf16*)&raw;
  float v[8], ss = 0.f;
  #pragma unroll
  for (int j = 0; j < 8; j++) { v[j] = __bfloat162float(hb[j]); ss += v[j] * v[j]; }
  ss = bsum4(ss, rs);
  float inv = rsqrtf(ss * (1.f / D_) + 1e-6f);
  int base = t * 8;
  #pragma unroll
  for (int j = 0; j < 8; j++) v[j] = v[j] * inv * w[base + j];
  if (do_rope) {
    int s = row % s_per_b;
    const float* fr = freqs + (size_t)s * (HD_ / 2) + ((base & (HD_ - 1)) >> 1);
    #pragma unroll
    for (int p = 0; p < 4; p++) {
      float ang = fr[p];
      float c = cosf(ang), sn = sinf(ang);
      float xr = v[2 * p], xi = v[2 * p + 1];
      v[2 * p]     = xr * c - xi * sn;
      v[2 * p + 1] = xr * sn + xi * c;
    }
  }
  float4 ow; bf16* ho = (bf16*)&ow;
  #pragma unroll
  for (int j = 0; j < 8; j++) ho[j] = __float2bfloat16(v[j]);
  *(float4*)(pr + (size_t)t * 8) = ow;
}

// in-place row softmax on bf16 scores, row length N = EPT*256
template <int EPT>
__global__ void k_softmax(bf16* __restrict__ buf, int N) {
  __shared__ float rs[4];
  int row = blockIdx.x, t = threadIdx.x;
  bf16* pr = buf + (size_t)row * N;
  float v[EPT], mx = -1e30f;
  #pragma unroll
  for (int j = 0; j < EPT; j++) { v[j] = __bfloat162float(pr[t + j * 256]); mx = fmaxf(mx, v[j]); }
  mx = bmax4(mx, rs);
  float s = 0.f;
  #pragma unroll
  for (int j = 0; j < EPT; j++) { v[j] = __expf(v[j] - mx); s += v[j]; }
  s = bsum4(s, rs);
  float invs = 1.f / s;
  #pragma unroll
  for (int j = 0; j < EPT; j++) pr[t + j * 256] = __float2bfloat16(v[j] * invs);
}

// ---------------- the MFMA GEMM: C = A(M,K) @ Bt(N,K)^T [+ epilogue] --------
// EPI 0: Cb = acc (+bias)          bf16
// EPI 1: Cb = acc * scale          bf16 (scores)
// EPI 2: Cf = Xin + (acc+bias)*e   f32 residual; optional Cb = bf16(Cf)
// EPI 3: Cb = gelu(acc+bias)       bf16 (FFN mid)
template <int EPI>
__global__ __launch_bounds__(256) void gemm_bt(
    const bf16* __restrict__ A, int lda, long long sA,
    const bf16* __restrict__ Bt, int ldb, long long sB,
    const float* __restrict__ bias,
    bf16* __restrict__ Cb, int ldc, long long sCb,
    float* __restrict__ Cf, const float* __restrict__ Xin,
    float scale, const float* __restrict__ evec, int s_per_b,
    int K) {
  __shared__ __align__(16) bf16 As[128][32];
  __shared__ __align__(16) bf16 Bs[128][32];
  const int z = blockIdx.z;
  A  += (long long)z * sA;
  Bt += (long long)z * sB;
  const int m0 = blockIdx.y * 128, n0 = blockIdx.x * 128;
  const int t = threadIdx.x;
  const int w = t >> 6, lane = t & 63;
  const int wrow = (w >> 1) * 64, wcol = (w & 1) * 64;
  const int quad = lane >> 4, l16 = lane & 15;

  f32x4 zero = {0.f, 0.f, 0.f, 0.f};
  f32x4 acc[4][4];
  #pragma unroll
  for (int i = 0; i < 4; i++)
    #pragma unroll
    for (int j = 0; j < 4; j++) acc[i][j] = zero;

  for (int k0 = 0; k0 < K; k0 += 32) {
    #pragma unroll
    for (int i = 0; i < 2; i++) {
      int c = t + i * 256;
      int r = c >> 2, col = (c & 3) * 8;
      *(float4*)(&As[r][col]) = *(const float4*)(A  + (size_t)(m0 + r) * lda + k0 + col);
      *(float4*)(&Bs[r][col]) = *(const float4*)(Bt + (size_t)(n0 + r) * ldb + k0 + col);
    }
    __syncthreads();
    bf16x8 af[4], bfr[4];
    #pragma unroll
    for (int mi = 0; mi < 4; mi++) af[mi]  = *(const bf16x8*)(&As[wrow + mi * 16 + l16][quad * 8]);
    #pragma unroll
    for (int ni = 0; ni < 4; ni++) bfr[ni] = *(const bf16x8*)(&Bs[wcol + ni * 16 + l16][quad * 8]);
    #pragma unroll
    for (int mi = 0; mi < 4; mi++)
      #pragma unroll
      for (int ni = 0; ni < 4; ni++)
        acc[mi][ni] = __builtin_amdgcn_mfma_f32_16x16x32_bf16(af[mi], bfr[ni], acc[mi][ni], 0, 0, 0);
    __syncthreads();
  }

  #pragma unroll
  for (int mi = 0; mi < 4; mi++) {
    #pragma unroll
    for (int r = 0; r < 4; r++) {
      int gm = m0 + wrow + mi * 16 + quad * 4 + r;
      #pragma unroll
      for (int ni = 0; ni < 4; ni++) {
        int gn = n0 + wcol + ni * 16 + l16;
        float v = acc[mi][ni][r];
        if (EPI == 0) {
          if (bias) v += bias[gn];
          Cb[(long long)z * sCb + (size_t)gm * ldc + gn] = __float2bfloat16(v);
        } else if (EPI == 1) {
          Cb[(long long)z * sCb + (size_t)gm * ldc + gn] = __float2bfloat16(v * scale);
        } else if (EPI == 3) {
          v += bias[gn];
          float g = 0.5f * v * (1.f + tanhf(0.7978845608028654f * (v + 0.044715f * v * v * v)));
          Cb[(long long)z * sCb + (size_t)gm * ldc + gn] = __float2bfloat16(g);
        } else {  // EPI 2: residual
          v += bias[gn];
          if (evec) v *= evec[(size_t)(gm / s_per_b) * ESTRIDE + gn];
          float o = Xin[(size_t)gm * ldc + gn] + v;
          Cf[(size_t)gm * ldc + gn] = o;
          if (Cb) Cb[(size_t)gm * ldc + gn] = __float2bfloat16(o);
        }
      }
    }
  }
}

// ---------------- host orchestration ----------------------------------------
extern "C" void kernel_launch(void* const* d_in, const int* in_sizes, int n_in,
                              void* d_out, int out_size, void* d_ws, size_t ws_size,
                              hipStream_t stream) {
  const float* x     = (const float*)d_in[0];
  const float* e     = (const float*)d_in[1];
  const float* ctx   = (const float*)d_in[2];
  const float* freqs = (const float*)d_in[3];
  const float* modu  = (const float*)d_in[4];
  const float* sq_w = (const float*)d_in[5];  const float* sq_b = (const float*)d_in[6];
  const float* sk_w = (const float*)d_in[7];  const float* sk_b = (const float*)d_in[8];
  const float* sv_w = (const float*)d_in[9];  const float* sv_b = (const float*)d_in[10];
  const float* so_w = (const float*)d_in[11]; const float* so_b = (const float*)d_in[12];
  const float* cq_w = (const float*)d_in[13]; const float* cq_b = (const float*)d_in[14];
  const float* ck_w = (const float*)d_in[15]; const float* ck_b = (const float*)d_in[16];
  const float* cv_w = (const float*)d_in[17]; const float* cv_b = (const float*)d_in[18];
  const float* co_w = (const float*)d_in[19]; const float* co_b = (const float*)d_in[20];
  const float* f1_w = (const float*)d_in[21]; const float* f1_b = (const float*)d_in[22];
  const float* f2_w = (const float*)d_in[23]; const float* f2_b = (const float*)d_in[24];
  const float* snq  = (const float*)d_in[25]; const float* snk  = (const float*)d_in[26];
  const float* cnq  = (const float*)d_in[27]; const float* cnk  = (const float*)d_in[28];
  float* out = (float*)d_out;     // doubles as the f32 residual accumulator

  const size_t MD = (size_t)B_ * S_ * D_;   // 8.39M elems

  char* W = (char*)d_ws;
  size_t off = 0;
  auto alloc = [&](size_t bytes) -> char* {
    char* p = W + off; off += (bytes + 255) & ~(size_t)255; return p;
  };
  float* em  = (float*)alloc((size_t)B_ * 6 * D_ * 4);
  bf16* wT   = (bf16*)alloc((size_t)F_ * D_ * 2);   // reusable transposed weights; scores overlays
  bf16* tx   = (bf16*)alloc(MD * 2);
  bf16* qb   = (bf16*)alloc(MD * 2);                // mid (4096x8192 bf16) overlays qb..attnout
  bf16* kb   = (bf16*)alloc(MD * 2);
  bf16* vb   = (bf16*)alloc(MD * 2);
  bf16* vt   = (bf16*)alloc(MD * 2);
  bf16* attnout = (bf16*)alloc(MD * 2);
  bf16* ctxb = (bf16*)alloc((size_t)B_ * LC_ * D_ * 2);
  bf16* kc   = (bf16*)alloc((size_t)B_ * LC_ * D_ * 2);
  bf16* vc   = (bf16*)alloc((size_t)B_ * LC_ * D_ * 2);
  bf16* vtc  = (bf16*)alloc((size_t)B_ * LC_ * D_ * 2);
  bf16* scores = wT;                                // overlay: lifetimes disjoint
  bf16* mid = qb;                                   // overlay: FFN mid
  if (off > ws_size) {                              // diagnostic fallback: out = x
    k_copy_f32<<<(int)(MD / 256), 256, 0, stream>>>(x, out);
    return;
  }

  const float qk_scale = 0.08838834764831845f;  // 1/sqrt(128)

  // ---- prep ----
  k_addmod<<<(B_ * 6 * D_) / 256, 256, 0, stream>>>(e, modu, em);
  k_f2b<<<(B_ * LC_ * D_) / 256, 256, 0, stream>>>(ctx, ctxb);

  // ---- self-attention branch ----
  k_ln_mod<<<B_ * S_, 256, 0, stream>>>(x, em, 0, 1, tx, S_);
  k_tr_f2b<<<dim3(D_ / 64, D_ / 64), 256, 0, stream>>>(sq_w, wT, D_, D_);
  gemm_bt<0><<<dim3(16, 32, 1), 256, 0, stream>>>(tx, D_, 0, wT, D_, 0, sq_b,
      qb, D_, 0, nullptr, nullptr, 1.f, nullptr, S_, D_);
  k_tr_f2b<<<dim3(D_ / 64, D_ / 64), 256, 0, stream>>>(sk_w, wT, D_, D_);
  gemm_bt<0><<<dim3(16, 32, 1), 256, 0, stream>>>(tx, D_, 0, wT, D_, 0, sk_b,
      kb, D_, 0, nullptr, nullptr, 1.f, nullptr, S_, D_);
  k_tr_f2b<<<dim3(D_ / 64, D_ / 64), 256, 0, stream>>>(sv_w, wT, D_, D_);
  gemm_bt<0><<<dim3(16, 32, 1), 256, 0, stream>>>(tx, D_, 0, wT, D_, 0, sv_b,
      vb, D_, 0, nullptr, nullptr, 1.f, nullptr, S_, D_);
  k_rms_rope<<<B_ * S_, 256, 0, stream>>>(qb, snq, freqs, 1, S_);
  k_rms_rope<<<B_ * S_, 256, 0, stream>>>(kb, snk, freqs, 1, S_);
  k_tr_b2b<<<dim3(D_ / 64, S_ / 64, B_), 256, 0, stream>>>(vb, vt, S_, D_,
      (long long)S_ * D_, (long long)D_ * S_);

  for (int b = 0; b < B_; b++) {
    for (int hc = 0; hc < 4; hc++) {  // 4 heads per chunk (scores: 4*S*S bf16 = 33.5 MB in wT)
      const bf16* Aq = qb + (size_t)b * S_ * D_ + hc * 4 * HD_;
      const bf16* Bk = kb + (size_t)b * S_ * D_ + hc * 4 * HD_;
      gemm_bt<1><<<dim3(16, 16, 4), 256, 0, stream>>>(Aq, D_, 128, Bk, D_, 128, nullptr,
          scores, S_, (long long)S_ * S_, nullptr, nullptr, qk_scale, nullptr, S_, HD_);
      k_softmax<8><<<4 * S_, 256, 0, stream>>>(scores, S_);
      const bf16* Bv = vt + ((size_t)b * D_ + hc * 4 * HD_) * S_;
      gemm_bt<0><<<dim3(1, 16, 4), 256, 0, stream>>>(scores, S_, (long long)S_ * S_,
          Bv, S_, (long long)HD_ * S_, nullptr,
          attnout + (size_t)b * S_ * D_ + hc * 4 * HD_, D_, 128,
          nullptr, nullptr, 1.f, nullptr, S_, S_);
    }
  }
  // out = x + (attn @ so_w + so_b) * e2 ; also write tx = bf16(out)
  k_tr_f2b<<<dim3(D_ / 64, D_ / 64), 256, 0, stream>>>(so_w, wT, D_, D_);
  gemm_bt<2><<<dim3(16, 32, 1), 256, 0, stream>>>(attnout, D_, 0, wT, D_, 0, so_b,
      tx, D_, 0, out, x, 1.f, em + 2 * D_, S_, D_);

  // ---- cross-attention branch ----
  k_tr_f2b<<<dim3(D_ / 64, D_ / 64), 256, 0, stream>>>(cq_w, wT, D_, D_);
  gemm_bt<0><<<dim3(16, 32, 1), 256, 0, stream>>>(tx, D_, 0, wT, D_, 0, cq_b,
      qb, D_, 0, nullptr, nullptr, 1.f, nullptr, S_, D_);
  k_rms_rope<<<B_ * S_, 256, 0, stream>>>(qb, cnq, nullptr, 0, S_);
  k_tr_f2b<<<dim3(D_ / 64, D_ / 64), 256, 0, stream>>>(ck_w, wT, D_, D_);
  gemm_bt<0><<<dim3(16, 8, 1), 256, 0, stream>>>(ctxb, D_, 0, wT, D_, 0, ck_b,
      kc, D_, 0, nullptr, nullptr, 1.f, nullptr, S_, D_);
  k_rms_rope<<<B_ * LC_, 256, 0, stream>>>(kc, cnk, nullptr, 0, S_);
  k_tr_f2b<<<dim3(D_ / 64, D_ / 64), 256, 0, stream>>>(cv_w, wT, D_, D_);
  gemm_bt<0><<<dim3(16, 8, 1), 256, 0, stream>>>(ctxb, D_, 0, wT, D_, 0, cv_b,
      vc, D_, 0, nullptr, nullptr, 1.f, nullptr, S_, D_);
  k_tr_b2b<<<dim3(D_ / 64, LC_ / 64, B_), 256, 0, stream>>>(vc, vtc, LC_, D_,
      (long long)LC_ * D_, (long long)D_ * LC_);

  for (int b = 0; b < B_; b++) {  // all 16 heads at once (scores: 16*S*LC bf16 = 33.5 MB)
    gemm_bt<1><<<dim3(4, 16, 16), 256, 0, stream>>>(qb + (size_t)b * S_ * D_, D_, 128,
        kc + (size_t)b * LC_ * D_, D_, 128, nullptr,
        scores, LC_, (long long)S_ * LC_, nullptr, nullptr, qk_scale, nullptr, S_, HD_);
    k_softmax<2><<<16 * S_, 256, 0, stream>>>(scores, LC_);
    gemm_bt<0><<<dim3(1, 16, 16), 256, 0, stream>>>(scores, LC_, (long long)S_ * LC_,
        vtc + (size_t)b * D_ * LC_, LC_, (long long)HD_ * LC_, nullptr,
        attnout + (size_t)b * S_ * D_, D_, 128, nullptr, nullptr, 1.f, nullptr, S_, LC_);
  }
  // out = out + attn @ co_w + co_b
  k_tr_f2b<<<dim3(D_ / 64, D_ / 64), 256, 0, stream>>>(co_w, wT, D_, D_);
  gemm_bt<2><<<dim3(16, 32, 1), 256, 0, stream>>>(attnout, D_, 0, wT, D_, 0, co_b,
      nullptr, D_, 0, out, out, 1.f, nullptr, S_, D_);

  // ---- FFN ----
  k_ln_mod<<<B_ * S_, 256, 0, stream>>>(out, em, 3, 4, tx, S_);
  k_tr_f2b<<<dim3(F_ / 64, D_ / 64), 256, 0, stream>>>(f1_w, wT, D_, F_);
  gemm_bt<3><<<dim3(64, 32, 1), 256, 0, stream>>>(tx, D_, 0, wT, D_, 0, f1_b,
      mid, F_, 0, nullptr, nullptr, 1.f, nullptr, S_, D_);
  k_tr_f2b<<<dim3(D_ / 64, F_ / 64), 256, 0, stream>>>(f2_w, wT, F_, D_);
  gemm_bt<2><<<dim3(16, 32, 1), 256, 0, stream>>>(mid, F_, 0, wT, F_, 0, f2_b,
      nullptr, D_, 0, out, out, 1.f, em + 5 * D_, S_, F_);
}

// Round 3
// 1919.039 us; speedup vs baseline: 1.1646x; 1.1646x over previous
//
#include <hip/hip_runtime.h>
#include <hip/hip_bf16.h>

using bf16 = __hip_bfloat16;
typedef __attribute__((ext_vector_type(8))) short bf16x8;
typedef __attribute__((ext_vector_type(4))) float f32x4;
typedef const __attribute__((address_space(1))) unsigned int* gp_t;  // global
typedef __attribute__((address_space(3))) unsigned int* sp_t;       // LDS

#define B_   2
#define S_   2048
#define D_   2048
#define H_   16
#define HD_  128
#define F_   8192
#define LC_  512
#define ESTRIDE (6*D_)   // em is (B,6,D); per-b stride

// ---------------- block reduction helpers (256 threads, 4 waves) ------------
__device__ __forceinline__ float bsum4(float v, float* rs) {
  #pragma unroll
  for (int o = 32; o; o >>= 1) v += __shfl_down(v, o, 64);
  int lane = threadIdx.x & 63, w = threadIdx.x >> 6;
  if (!lane) rs[w] = v;
  __syncthreads();
  float r = rs[0] + rs[1] + rs[2] + rs[3];
  __syncthreads();
  return r;
}
__device__ __forceinline__ float bmax4(float v, float* rs) {
  #pragma unroll
  for (int o = 32; o; o >>= 1) v = fmaxf(v, __shfl_down(v, o, 64));
  int lane = threadIdx.x & 63, w = threadIdx.x >> 6;
  if (!lane) rs[w] = v;
  __syncthreads();
  float r = fmaxf(fmaxf(rs[0], rs[1]), fmaxf(rs[2], rs[3]));
  __syncthreads();
  return r;
}

// ---------------- small elementwise kernels ---------------------------------
__global__ void k_addmod(const float* __restrict__ e, const float* __restrict__ mod,
                         float* __restrict__ em) {
  int i = blockIdx.x * 256 + threadIdx.x;        // B*6*D total
  em[i] = e[i] + mod[i % (6 * D_)];
}

__global__ void k_f2b(const float* __restrict__ in, bf16* __restrict__ out) {
  int i = blockIdx.x * 256 + threadIdx.x;
  out[i] = __float2bfloat16(in[i]);
}

__global__ void k_copy_f32(const float* __restrict__ in, float* __restrict__ out) {
  int i = blockIdx.x * 256 + threadIdx.x;
  out[i] = in[i];
}

// transpose+convert weights: in (K,N) f32 -> out (N,K) bf16
__global__ void k_tr_f2b(const float* __restrict__ in, bf16* __restrict__ out,
                         int K, int N) {
  __shared__ float tile[64][65];
  int kb = blockIdx.y << 6, nb = blockIdx.x << 6;
  int x = threadIdx.x & 63, y = threadIdx.x >> 6;
  #pragma unroll
  for (int r = y; r < 64; r += 4) tile[r][x] = in[(size_t)(kb + r) * N + nb + x];
  __syncthreads();
  #pragma unroll
  for (int r = y; r < 64; r += 4)
    out[(size_t)(nb + r) * K + kb + x] = __float2bfloat16(tile[x][r]);
}

// bf16 transpose, batched over z: in (R,C) -> out (C,R)
__global__ void k_tr_b2b(const bf16* __restrict__ in, bf16* __restrict__ out,
                         int R, int C, long long sIn, long long sOut) {
  in  += (long long)blockIdx.z * sIn;
  out += (long long)blockIdx.z * sOut;
  __shared__ bf16 tile[64][65];
  int rb = blockIdx.y << 6, cb = blockIdx.x << 6;
  int x = threadIdx.x & 63, y = threadIdx.x >> 6;
  #pragma unroll
  for (int r = y; r < 64; r += 4) tile[r][x] = in[(size_t)(rb + r) * C + cb + x];
  __syncthreads();
  #pragma unroll
  for (int r = y; r < 64; r += 4) out[(size_t)(cb + r) * R + rb + x] = tile[x][r];
}

// tx = LN(x) * (1 + e_i1) + e_i0, one block per row of 2048, bf16 out
__global__ void k_ln_mod(const float* __restrict__ x, const float* __restrict__ em,
                         int i0, int i1, bf16* __restrict__ out, int s_per_b) {
  __shared__ float rs[4];
  int row = blockIdx.x, t = threadIdx.x;
  int b = row / s_per_b;
  const float* xr = x + (size_t)row * D_;
  float vals[8], s = 0.f, ss = 0.f;
  #pragma unroll
  for (int j = 0; j < 8; j++) {
    float v = xr[t + j * 256];
    vals[j] = v; s += v; ss += v * v;
  }
  s  = bsum4(s, rs);
  ss = bsum4(ss, rs);
  float mean = s * (1.f / D_);
  float var  = ss * (1.f / D_) - mean * mean;
  float inv  = rsqrtf(var + 1e-6f);
  const float* e0 = em + ((size_t)b * 6 + i0) * D_;
  const float* e1 = em + ((size_t)b * 6 + i1) * D_;
  bf16* orow = out + (size_t)row * D_;
  #pragma unroll
  for (int j = 0; j < 8; j++) {
    int c = t + j * 256;
    orow[c] = __float2bfloat16((vals[j] - mean) * inv * (1.f + e1[c]) + e0[c]);
  }
}

// in-place rmsnorm over 2048 (+optional RoPE per 128-dim head), bf16 buffer
__global__ void k_rms_rope(bf16* __restrict__ buf, const float* __restrict__ w,
                           const float* __restrict__ freqs, int do_rope, int s_per_b) {
  __shared__ float rs[4];
  int row = blockIdx.x, t = threadIdx.x;
  bf16* pr = buf + (size_t)row * D_;
  float4 raw = *(const float4*)(pr + (size_t)t * 8);
  bf16* hb = (bf16*)&raw;
  float v[8], ss = 0.f;
  #pragma unroll
  for (int j = 0; j < 8; j++) { v[j] = __bfloat162float(hb[j]); ss += v[j] * v[j]; }
  ss = bsum4(ss, rs);
  float inv = rsqrtf(ss * (1.f / D_) + 1e-6f);
  int base = t * 8;
  #pragma unroll
  for (int j = 0; j < 8; j++) v[j] = v[j] * inv * w[base + j];
  if (do_rope) {
    int s = row % s_per_b;
    const float* fr = freqs + (size_t)s * (HD_ / 2) + ((base & (HD_ - 1)) >> 1);
    #pragma unroll
    for (int p = 0; p < 4; p++) {
      float ang = fr[p];
      float c = cosf(ang), sn = sinf(ang);
      float xr = v[2 * p], xi = v[2 * p + 1];
      v[2 * p]     = xr * c - xi * sn;
      v[2 * p + 1] = xr * sn + xi * c;
    }
  }
  float4 ow; bf16* ho = (bf16*)&ow;
  #pragma unroll
  for (int j = 0; j < 8; j++) ho[j] = __float2bfloat16(v[j]);
  *(float4*)(pr + (size_t)t * 8) = ow;
}

// in-place row softmax on bf16 scores, row length N = EPT*256
template <int EPT>
__global__ void k_softmax(bf16* __restrict__ buf, int N) {
  __shared__ float rs[4];
  int row = blockIdx.x, t = threadIdx.x;
  bf16* pr = buf + (size_t)row * N;
  float v[EPT], mx = -1e30f;
  #pragma unroll
  for (int j = 0; j < EPT; j++) { v[j] = __bfloat162float(pr[t + j * 256]); mx = fmaxf(mx, v[j]); }
  mx = bmax4(mx, rs);
  float s = 0.f;
  #pragma unroll
  for (int j = 0; j < EPT; j++) { v[j] = __expf(v[j] - mx); s += v[j]; }
  s = bsum4(s, rs);
  float invs = 1.f / s;
  #pragma unroll
  for (int j = 0; j < EPT; j++) pr[t + j * 256] = __float2bfloat16(v[j] * invs);
}

// ---------------- the MFMA GEMM: C = A(M,K) @ Bt(N,K)^T [+ epilogue] --------
// Staging: async global->LDS, 16B/lane (m97 pattern). LDS layout is linear in
// c = t + i*256 (byte offset 16c), so the wave-uniform dest base is
// w*64 + i*256 16B-chunks and HW's +lane*16 reproduces the old layout exactly.
// EPI 0: Cb = acc (+bias)          bf16
// EPI 1: Cb = acc * scale          bf16 (scores)
// EPI 2: Cf = Xin + (acc+bias)*e   f32 residual; optional Cb = bf16(Cf)
// EPI 3: Cb = gelu(acc+bias)       bf16 (FFN mid)
template <int EPI>
__global__ __launch_bounds__(256) void gemm_bt(
    const bf16* __restrict__ A, int lda, long long sA,
    const bf16* __restrict__ Bt, int ldb, long long sB,
    const float* __restrict__ bias,
    bf16* __restrict__ Cb, int ldc, long long sCb,
    float* __restrict__ Cf, const float* __restrict__ Xin,
    float scale, const float* __restrict__ evec, int s_per_b,
    int K) {
  __shared__ __align__(16) bf16 As[128][32];
  __shared__ __align__(16) bf16 Bs[128][32];
  const int z = blockIdx.z;
  A  += (long long)z * sA;
  Bt += (long long)z * sB;
  const int m0 = blockIdx.y * 128, n0 = blockIdx.x * 128;
  const int t = threadIdx.x;
  const int w = t >> 6, lane = t & 63;
  const int wrow = (w >> 1) * 64, wcol = (w & 1) * 64;
  const int quad = lane >> 4, l16 = lane & 15;

  f32x4 zero = {0.f, 0.f, 0.f, 0.f};
  f32x4 acc[4][4];
  #pragma unroll
  for (int i = 0; i < 4; i++)
    #pragma unroll
    for (int j = 0; j < 4; j++) acc[i][j] = zero;

  for (int k0 = 0; k0 < K; k0 += 32) {
    #pragma unroll
    for (int i = 0; i < 2; i++) {
      int c = t + i * 256;
      int r = c >> 2, col = (c & 3) * 8;
      __builtin_amdgcn_global_load_lds(
          (gp_t)(A + (size_t)(m0 + r) * lda + k0 + col),
          (sp_t)(&As[0][0] + (size_t)(w * 64 + i * 256) * 8), 16, 0, 0);
      __builtin_amdgcn_global_load_lds(
          (gp_t)(Bt + (size_t)(n0 + r) * ldb + k0 + col),
          (sp_t)(&Bs[0][0] + (size_t)(w * 64 + i * 256) * 8), 16, 0, 0);
    }
    __syncthreads();
    bf16x8 af[4], bfr[4];
    #pragma unroll
    for (int mi = 0; mi < 4; mi++) af[mi]  = *(const bf16x8*)(&As[wrow + mi * 16 + l16][quad * 8]);
    #pragma unroll
    for (int ni = 0; ni < 4; ni++) bfr[ni] = *(const bf16x8*)(&Bs[wcol + ni * 16 + l16][quad * 8]);
    #pragma unroll
    for (int mi = 0; mi < 4; mi++)
      #pragma unroll
      for (int ni = 0; ni < 4; ni++)
        acc[mi][ni] = __builtin_amdgcn_mfma_f32_16x16x32_bf16(af[mi], bfr[ni], acc[mi][ni], 0, 0, 0);
    __syncthreads();
  }

  #pragma unroll
  for (int mi = 0; mi < 4; mi++) {
    #pragma unroll
    for (int r = 0; r < 4; r++) {
      int gm = m0 + wrow + mi * 16 + quad * 4 + r;
      #pragma unroll
      for (int ni = 0; ni < 4; ni++) {
        int gn = n0 + wcol + ni * 16 + l16;
        float v = acc[mi][ni][r];
        if (EPI == 0) {
          if (bias) v += bias[gn];
          Cb[(long long)z * sCb + (size_t)gm * ldc + gn] = __float2bfloat16(v);
        } else if (EPI == 1) {
          Cb[(long long)z * sCb + (size_t)gm * ldc + gn] = __float2bfloat16(v * scale);
        } else if (EPI == 3) {
          v += bias[gn];
          float g = 0.5f * v * (1.f + tanhf(0.7978845608028654f * (v + 0.044715f * v * v * v)));
          Cb[(long long)z * sCb + (size_t)gm * ldc + gn] = __float2bfloat16(g);
        } else {  // EPI 2: residual
          v += bias[gn];
          if (evec) v *= evec[(size_t)(gm / s_per_b) * ESTRIDE + gn];
          float o = Xin[(size_t)gm * ldc + gn] + v;
          Cf[(size_t)gm * ldc + gn] = o;
          if (Cb) Cb[(size_t)gm * ldc + gn] = __float2bfloat16(o);
        }
      }
    }
  }
}

// ---------------- host orchestration ----------------------------------------
extern "C" void kernel_launch(void* const* d_in, const int* in_sizes, int n_in,
                              void* d_out, int out_size, void* d_ws, size_t ws_size,
                              hipStream_t stream) {
  const float* x     = (const float*)d_in[0];
  const float* e     = (const float*)d_in[1];
  const float* ctx   = (const float*)d_in[2];
  const float* freqs = (const float*)d_in[3];
  const float* modu  = (const float*)d_in[4];
  const float* sq_w = (const float*)d_in[5];  const float* sq_b = (const float*)d_in[6];
  const float* sk_w = (const float*)d_in[7];  const float* sk_b = (const float*)d_in[8];
  const float* sv_w = (const float*)d_in[9];  const float* sv_b = (const float*)d_in[10];
  const float* so_w = (const float*)d_in[11]; const float* so_b = (const float*)d_in[12];
  const float* cq_w = (const float*)d_in[13]; const float* cq_b = (const float*)d_in[14];
  const float* ck_w = (const float*)d_in[15]; const float* ck_b = (const float*)d_in[16];
  const float* cv_w = (const float*)d_in[17]; const float* cv_b = (const float*)d_in[18];
  const float* co_w = (const float*)d_in[19]; const float* co_b = (const float*)d_in[20];
  const float* f1_w = (const float*)d_in[21]; const float* f1_b = (const float*)d_in[22];
  const float* f2_w = (const float*)d_in[23]; const float* f2_b = (const float*)d_in[24];
  const float* snq  = (const float*)d_in[25]; const float* snk  = (const float*)d_in[26];
  const float* cnq  = (const float*)d_in[27]; const float* cnk  = (const float*)d_in[28];
  float* out = (float*)d_out;     // doubles as the f32 residual accumulator

  const size_t MD = (size_t)B_ * S_ * D_;   // 8.39M elems

  char* W = (char*)d_ws;
  size_t off = 0;
  auto alloc = [&](size_t bytes) -> char* {
    char* p = W + off; off += (bytes + 255) & ~(size_t)255; return p;
  };
  float* em  = (float*)alloc((size_t)B_ * 6 * D_ * 4);
  // Overlay plan (sizes already 256B-multiples, so no padding drift):
  //   [wT | vb | tx] = 33.5+16.8+16.8 MB = exactly 8*S*S*2 -> scores8 (self-attn)
  //   [qb | kb | vt | attnout] = 4*16.8 MB = exactly 4096*8192*2 -> mid (FFN)
  bf16* wT   = (bf16*)alloc((size_t)F_ * D_ * 2);   // transposed weights (f1-sized)
  bf16* vb   = (bf16*)alloc(MD * 2);
  bf16* tx   = (bf16*)alloc(MD * 2);
  bf16* qb   = (bf16*)alloc(MD * 2);
  bf16* kb   = (bf16*)alloc(MD * 2);
  bf16* vt   = (bf16*)alloc(MD * 2);
  bf16* attnout = (bf16*)alloc(MD * 2);
  bf16* ctxb = (bf16*)alloc((size_t)B_ * LC_ * D_ * 2);
  bf16* kc   = (bf16*)alloc((size_t)B_ * LC_ * D_ * 2);
  bf16* vc   = (bf16*)alloc((size_t)B_ * LC_ * D_ * 2);
  bf16* vtc  = (bf16*)alloc((size_t)B_ * LC_ * D_ * 2);
  bf16* scores8 = wT;   // 8-head self-attn scores: spans wT|vb|tx (all dead then)
  bf16* scoresC = wT;   // cross-attn scores: 16*S*LC*2 = 33.5 MB fits in wT alone
  bf16* mid = qb;       // FFN mid: spans qb|kb|vt|attnout
  if (off > ws_size) {  // diagnostic fallback: out = x
    k_copy_f32<<<(int)(MD / 256), 256, 0, stream>>>(x, out);
    return;
  }

  const float qk_scale = 0.08838834764831845f;  // 1/sqrt(128)

  // ---- prep ----
  k_addmod<<<(B_ * 6 * D_) / 256, 256, 0, stream>>>(e, modu, em);
  k_f2b<<<(B_ * LC_ * D_) / 256, 256, 0, stream>>>(ctx, ctxb);

  // ---- self-attention branch ----
  k_ln_mod<<<B_ * S_, 256, 0, stream>>>(x, em, 0, 1, tx, S_);
  k_tr_f2b<<<dim3(D_ / 64, D_ / 64), 256, 0, stream>>>(sq_w, wT, D_, D_);
  gemm_bt<0><<<dim3(16, 32, 1), 256, 0, stream>>>(tx, D_, 0, wT, D_, 0, sq_b,
      qb, D_, 0, nullptr, nullptr, 1.f, nullptr, S_, D_);
  k_tr_f2b<<<dim3(D_ / 64, D_ / 64), 256, 0, stream>>>(sk_w, wT, D_, D_);
  gemm_bt<0><<<dim3(16, 32, 1), 256, 0, stream>>>(tx, D_, 0, wT, D_, 0, sk_b,
      kb, D_, 0, nullptr, nullptr, 1.f, nullptr, S_, D_);
  k_tr_f2b<<<dim3(D_ / 64, D_ / 64), 256, 0, stream>>>(sv_w, wT, D_, D_);
  gemm_bt<0><<<dim3(16, 32, 1), 256, 0, stream>>>(tx, D_, 0, wT, D_, 0, sv_b,
      vb, D_, 0, nullptr, nullptr, 1.f, nullptr, S_, D_);
  k_rms_rope<<<B_ * S_, 256, 0, stream>>>(qb, snq, freqs, 1, S_);
  k_rms_rope<<<B_ * S_, 256, 0, stream>>>(kb, snk, freqs, 1, S_);
  k_tr_b2b<<<dim3(D_ / 64, S_ / 64, B_), 256, 0, stream>>>(vb, vt, S_, D_,
      (long long)S_ * D_, (long long)D_ * S_);
  // from here wT, vb, tx are dead -> scores8 overlay is live

  for (int b = 0; b < B_; b++) {
    for (int hc = 0; hc < 2; hc++) {  // 8 heads per chunk
      const int h0 = hc * 8;
      const bf16* Aq = qb + (size_t)b * S_ * D_ + h0 * HD_;
      const bf16* Bk = kb + (size_t)b * S_ * D_ + h0 * HD_;
      gemm_bt<1><<<dim3(16, 16, 8), 256, 0, stream>>>(Aq, D_, HD_, Bk, D_, HD_, nullptr,
          scores8, S_, (long long)S_ * S_, nullptr, nullptr, qk_scale, nullptr, S_, HD_);
      k_softmax<8><<<8 * S_, 256, 0, stream>>>(scores8, S_);
      const bf16* Bv = vt + ((size_t)b * D_ + h0 * HD_) * S_;
      gemm_bt<0><<<dim3(1, 16, 8), 256, 0, stream>>>(scores8, S_, (long long)S_ * S_,
          Bv, S_, (long long)HD_ * S_, nullptr,
          attnout + (size_t)b * S_ * D_ + h0 * HD_, D_, HD_,
          nullptr, nullptr, 1.f, nullptr, S_, S_);
    }
  }
  // out = x + (attn @ so_w + so_b) * e2 ; also write tx = bf16(out)
  k_tr_f2b<<<dim3(D_ / 64, D_ / 64), 256, 0, stream>>>(so_w, wT, D_, D_);
  gemm_bt<2><<<dim3(16, 32, 1), 256, 0, stream>>>(attnout, D_, 0, wT, D_, 0, so_b,
      tx, D_, 0, out, x, 1.f, em + 2 * D_, S_, D_);

  // ---- cross-attention branch ----
  k_tr_f2b<<<dim3(D_ / 64, D_ / 64), 256, 0, stream>>>(cq_w, wT, D_, D_);
  gemm_bt<0><<<dim3(16, 32, 1), 256, 0, stream>>>(tx, D_, 0, wT, D_, 0, cq_b,
      qb, D_, 0, nullptr, nullptr, 1.f, nullptr, S_, D_);
  k_rms_rope<<<B_ * S_, 256, 0, stream>>>(qb, cnq, nullptr, 0, S_);
  k_tr_f2b<<<dim3(D_ / 64, D_ / 64), 256, 0, stream>>>(ck_w, wT, D_, D_);
  gemm_bt<0><<<dim3(16, 8, 1), 256, 0, stream>>>(ctxb, D_, 0, wT, D_, 0, ck_b,
      kc, D_, 0, nullptr, nullptr, 1.f, nullptr, S_, D_);
  k_rms_rope<<<B_ * LC_, 256, 0, stream>>>(kc, cnk, nullptr, 0, S_);
  k_tr_f2b<<<dim3(D_ / 64, D_ / 64), 256, 0, stream>>>(cv_w, wT, D_, D_);
  gemm_bt<0><<<dim3(16, 8, 1), 256, 0, stream>>>(ctxb, D_, 0, wT, D_, 0, cv_b,
      vc, D_, 0, nullptr, nullptr, 1.f, nullptr, S_, D_);
  k_tr_b2b<<<dim3(D_ / 64, LC_ / 64, B_), 256, 0, stream>>>(vc, vtc, LC_, D_,
      (long long)LC_ * D_, (long long)D_ * LC_);

  for (int b = 0; b < B_; b++) {  // all 16 heads at once (16*S*LC*2 = 33.5 MB)
    gemm_bt<1><<<dim3(4, 16, 16), 256, 0, stream>>>(qb + (size_t)b * S_ * D_, D_, HD_,
        kc + (size_t)b * LC_ * D_, D_, HD_, nullptr,
        scoresC, LC_, (long long)S_ * LC_, nullptr, nullptr, qk_scale, nullptr, S_, HD_);
    k_softmax<2><<<16 * S_, 256, 0, stream>>>(scoresC, LC_);
    gemm_bt<0><<<dim3(1, 16, 16), 256, 0, stream>>>(scoresC, LC_, (long long)S_ * LC_,
        vtc + (size_t)b * D_ * LC_, LC_, (long long)HD_ * LC_, nullptr,
        attnout + (size_t)b * S_ * D_, D_, HD_, nullptr, nullptr, 1.f, nullptr, S_, LC_);
  }
  // out = out + attn @ co_w + co_b
  k_tr_f2b<<<dim3(D_ / 64, D_ / 64), 256, 0, stream>>>(co_w, wT, D_, D_);
  gemm_bt<2><<<dim3(16, 32, 1), 256, 0, stream>>>(attnout, D_, 0, wT, D_, 0, co_b,
      nullptr, D_, 0, out, out, 1.f, nullptr, S_, D_);

  // ---- FFN ----
  k_ln_mod<<<B_ * S_, 256, 0, stream>>>(out, em, 3, 4, tx, S_);
  k_tr_f2b<<<dim3(F_ / 64, D_ / 64), 256, 0, stream>>>(f1_w, wT, D_, F_);
  gemm_bt<3><<<dim3(64, 32, 1), 256, 0, stream>>>(tx, D_, 0, wT, D_, 0, f1_b,
      mid, F_, 0, nullptr, nullptr, 1.f, nullptr, S_, D_);
  k_tr_f2b<<<dim3(D_ / 64, F_ / 64), 256, 0, stream>>>(f2_w, wT, F_, D_);
  gemm_bt<2><<<dim3(16, 32, 1), 256, 0, stream>>>(mid, F_, 0, wT, F_, 0, f2_b,
      nullptr, D_, 0, out, out, 1.f, em + 5 * D_, S_, F_);
}

// Round 4
// 1860.262 us; speedup vs baseline: 1.2014x; 1.0316x over previous
//
#include <hip/hip_runtime.h>
#include <hip/hip_bf16.h>

using bf16 = __hip_bfloat16;
typedef __attribute__((ext_vector_type(8))) short bf16x8;
typedef __attribute__((ext_vector_type(4))) float f32x4;
typedef const __attribute__((address_space(1))) unsigned int* gp_t;  // global
typedef __attribute__((address_space(3))) unsigned int* sp_t;       // LDS

#define B_   2
#define S_   2048
#define D_   2048
#define H_   16
#define HD_  128
#define F_   8192
#define LC_  512
#define ESTRIDE (6*D_)   // em is (B,6,D); per-b stride

// ---------------- block reduction helpers (256 threads, 4 waves) ------------
__device__ __forceinline__ float bsum4(float v, float* rs) {
  #pragma unroll
  for (int o = 32; o; o >>= 1) v += __shfl_down(v, o, 64);
  int lane = threadIdx.x & 63, w = threadIdx.x >> 6;
  if (!lane) rs[w] = v;
  __syncthreads();
  float r = rs[0] + rs[1] + rs[2] + rs[3];
  __syncthreads();
  return r;
}
__device__ __forceinline__ float bmax4(float v, float* rs) {
  #pragma unroll
  for (int o = 32; o; o >>= 1) v = fmaxf(v, __shfl_down(v, o, 64));
  int lane = threadIdx.x & 63, w = threadIdx.x >> 6;
  if (!lane) rs[w] = v;
  __syncthreads();
  float r = fmaxf(fmaxf(rs[0], rs[1]), fmaxf(rs[2], rs[3]));
  __syncthreads();
  return r;
}

// ---------------- small elementwise kernels ---------------------------------
__global__ void k_addmod(const float* __restrict__ e, const float* __restrict__ mod,
                         float* __restrict__ em) {
  int i = blockIdx.x * 256 + threadIdx.x;        // B*6*D total
  em[i] = e[i] + mod[i % (6 * D_)];
}

__global__ void k_f2b(const float* __restrict__ in, bf16* __restrict__ out) {
  int i = blockIdx.x * 256 + threadIdx.x;
  out[i] = __float2bfloat16(in[i]);
}

__global__ void k_copy_f32(const float* __restrict__ in, float* __restrict__ out) {
  int i = blockIdx.x * 256 + threadIdx.x;
  out[i] = in[i];
}

// transpose+convert weights: in (K,N) f32 -> out (N,K) bf16
__global__ void k_tr_f2b(const float* __restrict__ in, bf16* __restrict__ out,
                         int K, int N) {
  __shared__ float tile[64][65];
  int kb = blockIdx.y << 6, nb = blockIdx.x << 6;
  int x = threadIdx.x & 63, y = threadIdx.x >> 6;
  #pragma unroll
  for (int r = y; r < 64; r += 4) tile[r][x] = in[(size_t)(kb + r) * N + nb + x];
  __syncthreads();
  #pragma unroll
  for (int r = y; r < 64; r += 4)
    out[(size_t)(nb + r) * K + kb + x] = __float2bfloat16(tile[x][r]);
}

// bf16 transpose, batched over z: in (R,C) -> out (C,R)
__global__ void k_tr_b2b(const bf16* __restrict__ in, bf16* __restrict__ out,
                         int R, int C, long long sIn, long long sOut) {
  in  += (long long)blockIdx.z * sIn;
  out += (long long)blockIdx.z * sOut;
  __shared__ bf16 tile[64][65];
  int rb = blockIdx.y << 6, cb = blockIdx.x << 6;
  int x = threadIdx.x & 63, y = threadIdx.x >> 6;
  #pragma unroll
  for (int r = y; r < 64; r += 4) tile[r][x] = in[(size_t)(rb + r) * C + cb + x];
  __syncthreads();
  #pragma unroll
  for (int r = y; r < 64; r += 4) out[(size_t)(cb + r) * R + rb + x] = tile[x][r];
}

// tx = LN(x) * (1 + e_i1) + e_i0, one block per row of 2048, bf16 out
__global__ void k_ln_mod(const float* __restrict__ x, const float* __restrict__ em,
                         int i0, int i1, bf16* __restrict__ out, int s_per_b) {
  __shared__ float rs[4];
  int row = blockIdx.x, t = threadIdx.x;
  int b = row / s_per_b;
  const float* xr = x + (size_t)row * D_;
  float vals[8], s = 0.f, ss = 0.f;
  #pragma unroll
  for (int j = 0; j < 8; j++) {
    float v = xr[t + j * 256];
    vals[j] = v; s += v; ss += v * v;
  }
  s  = bsum4(s, rs);
  ss = bsum4(ss, rs);
  float mean = s * (1.f / D_);
  float var  = ss * (1.f / D_) - mean * mean;
  float inv  = rsqrtf(var + 1e-6f);
  const float* e0 = em + ((size_t)b * 6 + i0) * D_;
  const float* e1 = em + ((size_t)b * 6 + i1) * D_;
  bf16* orow = out + (size_t)row * D_;
  #pragma unroll
  for (int j = 0; j < 8; j++) {
    int c = t + j * 256;
    orow[c] = __float2bfloat16((vals[j] - mean) * inv * (1.f + e1[c]) + e0[c]);
  }
}

// in-place rmsnorm over 2048 (+optional RoPE per 128-dim head), bf16 buffer
__global__ void k_rms_rope(bf16* __restrict__ buf, const float* __restrict__ w,
                           const float* __restrict__ freqs, int do_rope, int s_per_b) {
  __shared__ float rs[4];
  int row = blockIdx.x, t = threadIdx.x;
  bf16* pr = buf + (size_t)row * D_;
  float4 raw = *(const float4*)(pr + (size_t)t * 8);
  bf16* hb = (bf16*)&raw;
  float v[8], ss = 0.f;
  #pragma unroll
  for (int j = 0; j < 8; j++) { v[j] = __bfloat162float(hb[j]); ss += v[j] * v[j]; }
  ss = bsum4(ss, rs);
  float inv = rsqrtf(ss * (1.f / D_) + 1e-6f);
  int base = t * 8;
  #pragma unroll
  for (int j = 0; j < 8; j++) v[j] = v[j] * inv * w[base + j];
  if (do_rope) {
    int s = row % s_per_b;
    const float* fr = freqs + (size_t)s * (HD_ / 2) + ((base & (HD_ - 1)) >> 1);
    #pragma unroll
    for (int p = 0; p < 4; p++) {
      float ang = fr[p];
      float c = cosf(ang), sn = sinf(ang);
      float xr = v[2 * p], xi = v[2 * p + 1];
      v[2 * p]     = xr * c - xi * sn;
      v[2 * p + 1] = xr * sn + xi * c;
    }
  }
  float4 ow; bf16* ho = (bf16*)&ow;
  #pragma unroll
  for (int j = 0; j < 8; j++) ho[j] = __float2bfloat16(v[j]);
  *(float4*)(pr + (size_t)t * 8) = ow;
}

// in-place row softmax on bf16 scores, row length N = EPT*256
template <int EPT>
__global__ void k_softmax(bf16* __restrict__ buf, int N) {
  __shared__ float rs[4];
  int row = blockIdx.x, t = threadIdx.x;
  bf16* pr = buf + (size_t)row * N;
  float v[EPT], mx = -1e30f;
  #pragma unroll
  for (int j = 0; j < EPT; j++) { v[j] = __bfloat162float(pr[t + j * 256]); mx = fmaxf(mx, v[j]); }
  mx = bmax4(mx, rs);
  float s = 0.f;
  #pragma unroll
  for (int j = 0; j < EPT; j++) { v[j] = __expf(v[j] - mx); s += v[j]; }
  s = bsum4(s, rs);
  float invs = 1.f / s;
  #pragma unroll
  for (int j = 0; j < EPT; j++) pr[t + j * 256] = __float2bfloat16(v[j] * invs);
}

// XCD-stripe swizzle: when Nx%8==0, give each XCD (flat%8, assuming round-robin
// dispatch) a stripe of Nx/8 B-column-tiles so its private 4MB L2 keeps the
// stripe resident across the y sweep; A-panels stream through L3. Bijective.
__device__ __forceinline__ void xcd_swizzle(int& bx, int& by) {
  int nx = gridDim.x, ny = gridDim.y;
  if ((nx & 7) == 0) {
    int flat = by * nx + bx;
    int xcd = flat & 7;
    int idx = flat >> 3;
    int sx = nx >> 3;
    bx = xcd * sx + (idx % sx);
    by = idx / sx;
    (void)ny;
  }
}

// ---------------- the MFMA GEMM: C = A(M,K) @ Bt(N,K)^T [+ epilogue] --------
// Staging: async global->LDS, 16B/lane (m97 pattern).
// EPI 0: Cb = acc (+bias)          bf16
// EPI 1: Cb = acc * scale          bf16 (scores)
// EPI 2: Cf = Xin + (acc+bias)*e   f32 residual; optional Cb = bf16(Cf)
// EPI 3: Cb = gelu(acc+bias)       bf16 (FFN mid)
template <int EPI>
__global__ __launch_bounds__(256) void gemm_bt(
    const bf16* __restrict__ A, int lda, long long sA,
    const bf16* __restrict__ Bt, int ldb, long long sB,
    const float* __restrict__ bias,
    bf16* __restrict__ Cb, int ldc, long long sCb,
    float* __restrict__ Cf, const float* __restrict__ Xin,
    float scale, const float* __restrict__ evec, int s_per_b,
    int K) {
  __shared__ __align__(16) bf16 As[128][32];
  __shared__ __align__(16) bf16 Bs[128][32];
  const int z = blockIdx.z;
  A  += (long long)z * sA;
  Bt += (long long)z * sB;
  int bx = blockIdx.x, by = blockIdx.y;
  xcd_swizzle(bx, by);
  const int m0 = by * 128, n0 = bx * 128;
  const int t = threadIdx.x;
  const int w = t >> 6, lane = t & 63;
  const int wrow = (w >> 1) * 64, wcol = (w & 1) * 64;
  const int quad = lane >> 4, l16 = lane & 15;

  f32x4 zero = {0.f, 0.f, 0.f, 0.f};
  f32x4 acc[4][4];
  #pragma unroll
  for (int i = 0; i < 4; i++)
    #pragma unroll
    for (int j = 0; j < 4; j++) acc[i][j] = zero;

  for (int k0 = 0; k0 < K; k0 += 32) {
    #pragma unroll
    for (int i = 0; i < 2; i++) {
      int c = t + i * 256;
      int r = c >> 2, col = (c & 3) * 8;
      __builtin_amdgcn_global_load_lds(
          (gp_t)(A + (size_t)(m0 + r) * lda + k0 + col),
          (sp_t)(&As[0][0] + (size_t)(w * 64 + i * 256) * 8), 16, 0, 0);
      __builtin_amdgcn_global_load_lds(
          (gp_t)(Bt + (size_t)(n0 + r) * ldb + k0 + col),
          (sp_t)(&Bs[0][0] + (size_t)(w * 64 + i * 256) * 8), 16, 0, 0);
    }
    __syncthreads();
    bf16x8 af[4], bfr[4];
    #pragma unroll
    for (int mi = 0; mi < 4; mi++) af[mi]  = *(const bf16x8*)(&As[wrow + mi * 16 + l16][quad * 8]);
    #pragma unroll
    for (int ni = 0; ni < 4; ni++) bfr[ni] = *(const bf16x8*)(&Bs[wcol + ni * 16 + l16][quad * 8]);
    #pragma unroll
    for (int mi = 0; mi < 4; mi++)
      #pragma unroll
      for (int ni = 0; ni < 4; ni++)
        acc[mi][ni] = __builtin_amdgcn_mfma_f32_16x16x32_bf16(af[mi], bfr[ni], acc[mi][ni], 0, 0, 0);
    __syncthreads();
  }

  #pragma unroll
  for (int mi = 0; mi < 4; mi++) {
    #pragma unroll
    for (int r = 0; r < 4; r++) {
      int gm = m0 + wrow + mi * 16 + quad * 4 + r;
      #pragma unroll
      for (int ni = 0; ni < 4; ni++) {
        int gn = n0 + wcol + ni * 16 + l16;
        float v = acc[mi][ni][r];
        if (EPI == 0) {
          if (bias) v += bias[gn];
          Cb[(long long)z * sCb + (size_t)gm * ldc + gn] = __float2bfloat16(v);
        } else if (EPI == 1) {
          Cb[(long long)z * sCb + (size_t)gm * ldc + gn] = __float2bfloat16(v * scale);
        } else if (EPI == 3) {
          v += bias[gn];
          float g = 0.5f * v * (1.f + tanhf(0.7978845608028654f * (v + 0.044715f * v * v * v)));
          Cb[(long long)z * sCb + (size_t)gm * ldc + gn] = __float2bfloat16(g);
        } else {  // EPI 2: residual
          v += bias[gn];
          if (evec) v *= evec[(size_t)(gm / s_per_b) * ESTRIDE + gn];
          float o = Xin[(size_t)gm * ldc + gn] + v;
          Cf[(size_t)gm * ldc + gn] = o;
          if (Cb) Cb[(size_t)gm * ldc + gn] = __float2bfloat16(o);
        }
      }
    }
  }
}

// 64x64-tile GEMM (no bias/epilogue) for narrow-N problems (PV: N=128).
// 4 waves, each computing a 32x32 quadrant (2x2 MFMA tiles, 16 AGPR).
__global__ __launch_bounds__(256) void gemm64(
    const bf16* __restrict__ A, int lda, long long sA,
    const bf16* __restrict__ Bt, int ldb, long long sB,
    bf16* __restrict__ Cb, int ldc, long long sCb,
    int K) {
  __shared__ __align__(16) bf16 As[64][32];
  __shared__ __align__(16) bf16 Bs[64][32];
  const int z = blockIdx.z;
  A  += (long long)z * sA;
  Bt += (long long)z * sB;
  const int m0 = blockIdx.y * 64, n0 = blockIdx.x * 64;
  const int t = threadIdx.x;
  const int w = t >> 6, lane = t & 63;
  const int wrow = (w >> 1) * 32, wcol = (w & 1) * 32;
  const int quad = lane >> 4, l16 = lane & 15;

  f32x4 zero = {0.f, 0.f, 0.f, 0.f};
  f32x4 acc[2][2];
  #pragma unroll
  for (int i = 0; i < 2; i++)
    #pragma unroll
    for (int j = 0; j < 2; j++) acc[i][j] = zero;

  for (int k0 = 0; k0 < K; k0 += 32) {
    {
      int r = t >> 2, col = (t & 3) * 8;
      __builtin_amdgcn_global_load_lds(
          (gp_t)(A + (size_t)(m0 + r) * lda + k0 + col),
          (sp_t)(&As[0][0] + (size_t)(w * 64) * 8), 16, 0, 0);
      __builtin_amdgcn_global_load_lds(
          (gp_t)(Bt + (size_t)(n0 + r) * ldb + k0 + col),
          (sp_t)(&Bs[0][0] + (size_t)(w * 64) * 8), 16, 0, 0);
    }
    __syncthreads();
    bf16x8 af[2], bfr[2];
    #pragma unroll
    for (int mi = 0; mi < 2; mi++) af[mi]  = *(const bf16x8*)(&As[wrow + mi * 16 + l16][quad * 8]);
    #pragma unroll
    for (int ni = 0; ni < 2; ni++) bfr[ni] = *(const bf16x8*)(&Bs[wcol + ni * 16 + l16][quad * 8]);
    #pragma unroll
    for (int mi = 0; mi < 2; mi++)
      #pragma unroll
      for (int ni = 0; ni < 2; ni++)
        acc[mi][ni] = __builtin_amdgcn_mfma_f32_16x16x32_bf16(af[mi], bfr[ni], acc[mi][ni], 0, 0, 0);
    __syncthreads();
  }

  #pragma unroll
  for (int mi = 0; mi < 2; mi++) {
    #pragma unroll
    for (int r = 0; r < 4; r++) {
      int gm = m0 + wrow + mi * 16 + quad * 4 + r;
      #pragma unroll
      for (int ni = 0; ni < 2; ni++) {
        int gn = n0 + wcol + ni * 16 + l16;
        Cb[(long long)z * sCb + (size_t)gm * ldc + gn] = __float2bfloat16(acc[mi][ni][r]);
      }
    }
  }
}

// ---------------- host orchestration ----------------------------------------
extern "C" void kernel_launch(void* const* d_in, const int* in_sizes, int n_in,
                              void* d_out, int out_size, void* d_ws, size_t ws_size,
                              hipStream_t stream) {
  const float* x     = (const float*)d_in[0];
  const float* e     = (const float*)d_in[1];
  const float* ctx   = (const float*)d_in[2];
  const float* freqs = (const float*)d_in[3];
  const float* modu  = (const float*)d_in[4];
  const float* sq_w = (const float*)d_in[5];  const float* sq_b = (const float*)d_in[6];
  const float* sk_w = (const float*)d_in[7];  const float* sk_b = (const float*)d_in[8];
  const float* sv_w = (const float*)d_in[9];  const float* sv_b = (const float*)d_in[10];
  const float* so_w = (const float*)d_in[11]; const float* so_b = (const float*)d_in[12];
  const float* cq_w = (const float*)d_in[13]; const float* cq_b = (const float*)d_in[14];
  const float* ck_w = (const float*)d_in[15]; const float* ck_b = (const float*)d_in[16];
  const float* cv_w = (const float*)d_in[17]; const float* cv_b = (const float*)d_in[18];
  const float* co_w = (const float*)d_in[19]; const float* co_b = (const float*)d_in[20];
  const float* f1_w = (const float*)d_in[21]; const float* f1_b = (const float*)d_in[22];
  const float* f2_w = (const float*)d_in[23]; const float* f2_b = (const float*)d_in[24];
  const float* snq  = (const float*)d_in[25]; const float* snk  = (const float*)d_in[26];
  const float* cnq  = (const float*)d_in[27]; const float* cnk  = (const float*)d_in[28];
  float* out = (float*)d_out;     // doubles as the f32 residual accumulator

  const size_t MD = (size_t)B_ * S_ * D_;   // 8.39M elems

  char* W = (char*)d_ws;
  size_t off = 0;
  auto alloc = [&](size_t bytes) -> char* {
    char* p = W + off; off += (bytes + 255) & ~(size_t)255; return p;
  };
  float* em  = (float*)alloc((size_t)B_ * 6 * D_ * 4);
  // Overlay plan (sizes already 256B-multiples, so no padding drift):
  //   [wT | vb | tx] = 33.5+16.8+16.8 MB = exactly 8*S*S*2 -> scores8 (self-attn)
  //   [qb | kb | vt | attnout] = 4*16.8 MB = exactly 4096*8192*2 -> mid (FFN)
  bf16* wT   = (bf16*)alloc((size_t)F_ * D_ * 2);   // transposed weights (f1-sized)
  bf16* vb   = (bf16*)alloc(MD * 2);
  bf16* tx   = (bf16*)alloc(MD * 2);
  bf16* qb   = (bf16*)alloc(MD * 2);
  bf16* kb   = (bf16*)alloc(MD * 2);
  bf16* vt   = (bf16*)alloc(MD * 2);
  bf16* attnout = (bf16*)alloc(MD * 2);
  bf16* ctxb = (bf16*)alloc((size_t)B_ * LC_ * D_ * 2);
  bf16* kc   = (bf16*)alloc((size_t)B_ * LC_ * D_ * 2);
  bf16* vc   = (bf16*)alloc((size_t)B_ * LC_ * D_ * 2);
  bf16* vtc  = (bf16*)alloc((size_t)B_ * LC_ * D_ * 2);
  bf16* scores8 = wT;   // 8-head self-attn scores: spans wT|vb|tx (all dead then)
  bf16* scoresC = wT;   // cross-attn scores: 16*S*LC*2 = 33.5 MB fits in wT alone
  bf16* mid = qb;       // FFN mid: spans qb|kb|vt|attnout
  if (off > ws_size) {  // diagnostic fallback: out = x
    k_copy_f32<<<(int)(MD / 256), 256, 0, stream>>>(x, out);
    return;
  }

  const float qk_scale = 0.08838834764831845f;  // 1/sqrt(128)

  // ---- prep ----
  k_addmod<<<(B_ * 6 * D_) / 256, 256, 0, stream>>>(e, modu, em);
  k_f2b<<<(B_ * LC_ * D_) / 256, 256, 0, stream>>>(ctx, ctxb);

  // ---- self-attention branch ----
  k_ln_mod<<<B_ * S_, 256, 0, stream>>>(x, em, 0, 1, tx, S_);
  k_tr_f2b<<<dim3(D_ / 64, D_ / 64), 256, 0, stream>>>(sq_w, wT, D_, D_);
  gemm_bt<0><<<dim3(16, 32, 1), 256, 0, stream>>>(tx, D_, 0, wT, D_, 0, sq_b,
      qb, D_, 0, nullptr, nullptr, 1.f, nullptr, S_, D_);
  k_tr_f2b<<<dim3(D_ / 64, D_ / 64), 256, 0, stream>>>(sk_w, wT, D_, D_);
  gemm_bt<0><<<dim3(16, 32, 1), 256, 0, stream>>>(tx, D_, 0, wT, D_, 0, sk_b,
      kb, D_, 0, nullptr, nullptr, 1.f, nullptr, S_, D_);
  k_tr_f2b<<<dim3(D_ / 64, D_ / 64), 256, 0, stream>>>(sv_w, wT, D_, D_);
  gemm_bt<0><<<dim3(16, 32, 1), 256, 0, stream>>>(tx, D_, 0, wT, D_, 0, sv_b,
      vb, D_, 0, nullptr, nullptr, 1.f, nullptr, S_, D_);
  k_rms_rope<<<B_ * S_, 256, 0, stream>>>(qb, snq, freqs, 1, S_);
  k_rms_rope<<<B_ * S_, 256, 0, stream>>>(kb, snk, freqs, 1, S_);
  k_tr_b2b<<<dim3(D_ / 64, S_ / 64, B_), 256, 0, stream>>>(vb, vt, S_, D_,
      (long long)S_ * D_, (long long)D_ * S_);
  // from here wT, vb, tx are dead -> scores8 overlay is live

  for (int b = 0; b < B_; b++) {
    for (int hc = 0; hc < 2; hc++) {  // 8 heads per chunk
      const int h0 = hc * 8;
      const bf16* Aq = qb + (size_t)b * S_ * D_ + h0 * HD_;
      const bf16* Bk = kb + (size_t)b * S_ * D_ + h0 * HD_;
      gemm_bt<1><<<dim3(16, 16, 8), 256, 0, stream>>>(Aq, D_, HD_, Bk, D_, HD_, nullptr,
          scores8, S_, (long long)S_ * S_, nullptr, nullptr, qk_scale, nullptr, S_, HD_);
      k_softmax<8><<<8 * S_, 256, 0, stream>>>(scores8, S_);
      const bf16* Bv = vt + ((size_t)b * D_ + h0 * HD_) * S_;
      gemm64<<<dim3(2, 32, 8), 256, 0, stream>>>(scores8, S_, (long long)S_ * S_,
          Bv, S_, (long long)HD_ * S_,
          attnout + (size_t)b * S_ * D_ + h0 * HD_, D_, HD_, S_);
    }
  }
  // out = x + (attn @ so_w + so_b) * e2 ; also write tx = bf16(out)
  k_tr_f2b<<<dim3(D_ / 64, D_ / 64), 256, 0, stream>>>(so_w, wT, D_, D_);
  gemm_bt<2><<<dim3(16, 32, 1), 256, 0, stream>>>(attnout, D_, 0, wT, D_, 0, so_b,
      tx, D_, 0, out, x, 1.f, em + 2 * D_, S_, D_);

  // ---- cross-attention branch ----
  k_tr_f2b<<<dim3(D_ / 64, D_ / 64), 256, 0, stream>>>(cq_w, wT, D_, D_);
  gemm_bt<0><<<dim3(16, 32, 1), 256, 0, stream>>>(tx, D_, 0, wT, D_, 0, cq_b,
      qb, D_, 0, nullptr, nullptr, 1.f, nullptr, S_, D_);
  k_rms_rope<<<B_ * S_, 256, 0, stream>>>(qb, cnq, nullptr, 0, S_);
  k_tr_f2b<<<dim3(D_ / 64, D_ / 64), 256, 0, stream>>>(ck_w, wT, D_, D_);
  gemm_bt<0><<<dim3(16, 8, 1), 256, 0, stream>>>(ctxb, D_, 0, wT, D_, 0, ck_b,
      kc, D_, 0, nullptr, nullptr, 1.f, nullptr, S_, D_);
  k_rms_rope<<<B_ * LC_, 256, 0, stream>>>(kc, cnk, nullptr, 0, S_);
  k_tr_f2b<<<dim3(D_ / 64, D_ / 64), 256, 0, stream>>>(cv_w, wT, D_, D_);
  gemm_bt<0><<<dim3(16, 8, 1), 256, 0, stream>>>(ctxb, D_, 0, wT, D_, 0, cv_b,
      vc, D_, 0, nullptr, nullptr, 1.f, nullptr, S_, D_);
  k_tr_b2b<<<dim3(D_ / 64, LC_ / 64, B_), 256, 0, stream>>>(vc, vtc, LC_, D_,
      (long long)LC_ * D_, (long long)D_ * LC_);

  for (int b = 0; b < B_; b++) {  // all 16 heads at once (16*S*LC*2 = 33.5 MB)
    gemm_bt<1><<<dim3(4, 16, 16), 256, 0, stream>>>(qb + (size_t)b * S_ * D_, D_, HD_,
        kc + (size_t)b * LC_ * D_, D_, HD_, nullptr,
        scoresC, LC_, (long long)S_ * LC_, nullptr, nullptr, qk_scale, nullptr, S_, HD_);
    k_softmax<2><<<16 * S_, 256, 0, stream>>>(scoresC, LC_);
    gemm64<<<dim3(2, 32, 16), 256, 0, stream>>>(scoresC, LC_, (long long)S_ * LC_,
        vtc + (size_t)b * D_ * LC_, LC_, (long long)HD_ * LC_,
        attnout + (size_t)b * S_ * D_, D_, HD_, LC_);
  }
  // out = out + attn @ co_w + co_b
  k_tr_f2b<<<dim3(D_ / 64, D_ / 64), 256, 0, stream>>>(co_w, wT, D_, D_);
  gemm_bt<2><<<dim3(16, 32, 1), 256, 0, stream>>>(attnout, D_, 0, wT, D_, 0, co_b,
      nullptr, D_, 0, out, out, 1.f, nullptr, S_, D_);

  // ---- FFN ----
  k_ln_mod<<<B_ * S_, 256, 0, stream>>>(out, em, 3, 4, tx, S_);
  k_tr_f2b<<<dim3(F_ / 64, D_ / 64), 256, 0, stream>>>(f1_w, wT, D_, F_);
  gemm_bt<3><<<dim3(64, 32, 1), 256, 0, stream>>>(tx, D_, 0, wT, D_, 0, f1_b,
      mid, F_, 0, nullptr, nullptr, 1.f, nullptr, S_, D_);
  k_tr_f2b<<<dim3(D_ / 64, F_ / 64), 256, 0, stream>>>(f2_w, wT, F_, D_);
  gemm_bt<2><<<dim3(16, 32, 1), 256, 0, stream>>>(mid, F_, 0, wT, F_, 0, f2_b,
      nullptr, D_, 0, out, out, 1.f, em + 5 * D_, S_, F_);
}